// Round 6
// baseline (24.241 us; speedup 1.0000x reference)
//
#include <hip/hip_runtime.h>
#include <math.h>

// inputs [B=1024, 7, 7, C=512] f32 NHWC; out [B, 512]:
//   out[b][0:22]          = top-22 of center pixel (3,3)  (k_c = 512%49)
//   out[b][22 + p*10 + j] = top-10 of pixel p             (k_pp = 512//49)
#define NPIX 49
#define C_CH 512
#define CENTER_PIX 24
#define K_PP 10
#define K_C 22
#define CENTER_BLOCKS 256   // FIRST: long-serial-latency waves start at t=0
#define MAIN_BLOCKS 3136    // x4 waves x4 pixels = 50176 pixels

__device__ __forceinline__ float ibc(int x) { return __int_as_float(x); }
__device__ __forceinline__ int fbc(float x) { return __float_as_int(x); }

// Descending compare-exchange.
__device__ __forceinline__ void ce(float& a, float& b) {
    const float mx = fmaxf(a, b), mn = fminf(a, b);
    a = mx; b = mn;
}

// Sort 8 descending — Batcher odd-even mergesort, 19 CE. (Proven R1-R5.)
__device__ __forceinline__ void sort8_desc(float* v) {
    ce(v[0],v[1]); ce(v[2],v[3]); ce(v[4],v[5]); ce(v[6],v[7]);
    ce(v[0],v[2]); ce(v[1],v[3]); ce(v[4],v[6]); ce(v[5],v[7]);
    ce(v[1],v[2]); ce(v[5],v[6]);
    ce(v[0],v[4]); ce(v[1],v[5]); ce(v[2],v[6]); ce(v[3],v[7]);
    ce(v[2],v[4]); ce(v[3],v[5]);
    ce(v[1],v[2]); ce(v[3],v[4]); ce(v[5],v[6]);
}

// Clean a cyclic-bitonic 10-seq to descending order. (Proven R4/R5.)
__device__ __forceinline__ void bitonic10_clean(float (&c)[10]) {
    ce(c[0],c[8]); ce(c[1],c[9]);
    ce(c[2],c[6]); ce(c[3],c[7]); ce(c[4],c[8]); ce(c[5],c[9]);
    ce(c[2],c[4]); ce(c[3],c[5]); ce(c[6],c[8]); ce(c[7],c[9]);
    ce(c[0],c[1]); ce(c[2],c[3]); ce(c[4],c[5]); ce(c[6],c[7]); ce(c[8],c[9]);
}

// Merge two descending sorted-8 lists -> descending sorted top-10, IN PLACE:
// high half of the bitonic split overwrites a, low half overwrites b (pairs
// (a[i], b[7-i]) are disjoint across i). Saves the 16-reg h/l temp set of the
// R4/R5 version; the comparator wiring is identical (bench-proven).
__device__ __forceinline__ void merge88_top10(float (&a)[8], float (&b)[8],
                                              float (&L)[10]) {
#pragma unroll
    for (int i = 0; i < 8; ++i) {
        const float mx = fmaxf(a[i], b[7 - i]);
        b[7 - i] = fminf(a[i], b[7 - i]);   // l: ranks 9..16 (cyclic bitonic)
        a[i] = mx;                          // h: top-8     (cyclic bitonic)
    }
    // clean h=a descending (bitonic-8)
    ce(a[0],a[4]); ce(a[1],a[5]); ce(a[2],a[6]); ce(a[3],a[7]);
    ce(a[0],a[2]); ce(a[1],a[3]); ce(a[4],a[6]); ce(a[5],a[7]);
    ce(a[0],a[1]); ce(a[2],a[3]); ce(a[4],a[5]); ce(a[6],a[7]);
    // sorted top-2 of l=b (bitonic-split tournament; valid since l is bitonic)
    const float m0 = fmaxf(b[0], b[4]), m1 = fmaxf(b[1], b[5]);
    const float m2 = fmaxf(b[2], b[6]), m3 = fmaxf(b[3], b[7]);
    const float n0 = fmaxf(m0, m2), n1 = fmaxf(m1, m3);
#pragma unroll
    for (int i = 0; i < 8; ++i) L[i] = a[i];
    L[8] = fmaxf(n0, n1);
    L[9] = fminf(n0, n1);
}

// a = top-10 of (sorted-10 a ∪ sorted-8 b). (Proven R5.)
__device__ __forceinline__ void merge8_into10(float (&a)[10], const float (&b)[8]) {
    float c[10];
    c[0] = a[0]; c[1] = a[1];
#pragma unroll
    for (int i = 2; i < 10; ++i) c[i] = fmaxf(a[i], b[9 - i]);
    bitonic10_clean(c);
#pragma unroll
    for (int i = 0; i < 10; ++i) a[i] = c[i];
}

// Cross-lane tree level: merge own sorted-10 with row-rotated partner's.
template <int CTRL>
__device__ __forceinline__ void tree_level(float (&T)[10]) {
    float c[10];
#pragma unroll
    for (int i = 0; i < 10; ++i) {
        const int s = fbc(T[9 - i]);
        const int p = __builtin_amdgcn_update_dpp(s, s, CTRL, 0xF, 0xF, false);
        c[i] = fmaxf(T[i], ibc(p));
    }
    bitonic10_clean(c);
#pragma unroll
    for (int i = 0; i < 10; ++i) T[i] = c[i];
}

// ---- center-pixel path (R2-proven serial extraction, 1024 waves only) ----
template <int CTRL>
__device__ __forceinline__ float dpp_maxf(float x) {
    const int xi = fbc(x);
    const int yi = __builtin_amdgcn_update_dpp(xi, xi, CTRL, 0xF, 0xF, false);
    return fmaxf(x, ibc(yi));
}

__device__ __forceinline__ float wave_max_uniform(float x) {
    x = dpp_maxf<0x111>(x);  // row_shr:1
    x = dpp_maxf<0x112>(x);  // row_shr:2
    x = dpp_maxf<0x114>(x);  // row_shr:4
    x = dpp_maxf<0x118>(x);  // row_shr:8
    x = dpp_maxf<0x142>(x);  // row_bcast15
    x = dpp_maxf<0x143>(x);  // row_bcast31
    return ibc(__builtin_amdgcn_readlane(fbc(x), 63));
}

__device__ __forceinline__ void round1(float (&v)[8], float& res, int lane, int it) {
    const float m = wave_max_uniform(v[0]);
    const unsigned long long msk = __ballot(v[0] == m);
    const int owner = __ffsll(msk) - 1;
    const bool own = (lane == owner);
    v[0] = own ? v[1] : v[0];
    v[1] = own ? v[2] : v[1];
    v[2] = own ? v[3] : v[2];
    v[3] = own ? v[4] : v[3];
    v[4] = own ? v[5] : v[4];
    v[5] = own ? v[6] : v[5];
    v[6] = own ? v[7] : v[6];
    v[7] = own ? -INFINITY : v[7];
    res = (lane == it) ? m : res;
}

// min-waves-per-EU = 8 -> VGPR cap 64. The main path's peak live set is now
// ~54-58 regs by construction (in-place merge + deferred batch-3/4 loads), so
// the cap should be met WITHOUT scratch spills (R5's peak was ~74 -> spill).
__global__ __launch_bounds__(256, 8) void
channel_topk_kernel(const float* __restrict__ in, float* __restrict__ out) {
    const int wid = threadIdx.x >> 6;
    const int lane = threadIdx.x & 63;

    if (blockIdx.x >= CENTER_BLOCKS) {
        // ---- main path: 16 lanes per pixel, 4 pixels per wave ----
        const int g = lane & 15;
        const int pix = ((blockIdx.x - CENTER_BLOCKS) * 4 + wid) * 4 + (lane >> 4);
        const float* src = in + (size_t)pix * C_CH + g * 4;

        // Batches 1+2 (channels g*4 + {0..3}*64 + k): 4 coalesced float4.
        const float4 t0 = *reinterpret_cast<const float4*>(src);
        const float4 t1 = *reinterpret_cast<const float4*>(src + 64);
        const float4 t2 = *reinterpret_cast<const float4*>(src + 128);
        const float4 t3 = *reinterpret_cast<const float4*>(src + 192);
        float a[8] = {t0.x, t0.y, t0.z, t0.w, t1.x, t1.y, t1.z, t1.w};
        float b[8] = {t2.x, t2.y, t2.z, t2.w, t3.x, t3.y, t3.z, t3.w};
        sort8_desc(a);
        sort8_desc(b);
        float L[10];
        merge88_top10(a, b, L);          // in place: a,b clobbered

        // Batch 3 loaded after the first merge: keeps peak regs ~55.
        const float4 t4 = *reinterpret_cast<const float4*>(src + 256);
        const float4 t5 = *reinterpret_cast<const float4*>(src + 320);
        float s1[8] = {t4.x, t4.y, t4.z, t4.w, t5.x, t5.y, t5.z, t5.w};
        sort8_desc(s1);
        merge8_into10(L, s1);

        // Batch 4.
        const float4 t6 = *reinterpret_cast<const float4*>(src + 384);
        const float4 t7 = *reinterpret_cast<const float4*>(src + 448);
        float s2[8] = {t6.x, t6.y, t6.z, t6.w, t7.x, t7.y, t7.z, t7.w};
        sort8_desc(s2);
        merge8_into10(L, s2);            // L = lane's top-10 of its 32 ch

        // rotate-merge across the 16-lane row: exact binary coverage.
        tree_level<0x121>(L);  // row_ror:1
        tree_level<0x122>(L);  // row_ror:2
        tree_level<0x124>(L);  // row_ror:4
        tree_level<0x128>(L);  // row_ror:8

        const int bb = pix / NPIX;
        const int p = pix - bb * NPIX;
        float r = L[0];
#pragma unroll
        for (int i = 1; i < 10; ++i) r = (g == i) ? L[i] : r;
        if (g < K_PP) out[(size_t)bb * C_CH + K_C + p * K_PP + g] = r;
    } else {
        // ---- center path: one wave per batch, top-22 of pixel (3,3) ----
        const int c = blockIdx.x * 4 + wid;  // batch 0..1023
        const float* src = in + ((size_t)c * NPIX + CENTER_PIX) * C_CH;
        const float4 a0 = *reinterpret_cast<const float4*>(src + lane * 4);
        const float4 a1 = *reinterpret_cast<const float4*>(src + 256 + lane * 4);
        float v[8] = {a0.x, a0.y, a0.z, a0.w, a1.x, a1.y, a1.z, a1.w};
        sort8_desc(v);
        float res = 0.0f;
#pragma unroll
        for (int it = 0; it < K_C; ++it) round1(v, res, lane, it);
        if (lane < K_C) out[(size_t)c * C_CH + lane] = res;
    }
}

extern "C" void kernel_launch(void* const* d_in, const int* in_sizes, int n_in,
                              void* d_out, int out_size, void* d_ws, size_t ws_size,
                              hipStream_t stream) {
    const float* in = (const float*)d_in[0];
    float* out = (float*)d_out;
    channel_topk_kernel<<<CENTER_BLOCKS + MAIN_BLOCKS, 256, 0, stream>>>(in, out);
}